// Round 5
// baseline (2303.913 us; speedup 1.0000x reference)
//
#include <hip/hip_runtime.h>
#include <hip/hip_bf16.h>

#define NN 4096
#define NI 16384   // N*I
#define HH 32

typedef __attribute__((ext_vector_type(8))) short short8;
typedef __attribute__((ext_vector_type(4))) float f32x4;

__device__ __forceinline__ short f2bs(float f) {
  __hip_bfloat16 b = __float2bfloat16(f);
  return *(short*)&b;
}
__device__ __forceinline__ float bs2f(short s) {
  __hip_bfloat16 b = *(__hip_bfloat16*)&s;
  return __bfloat162float(b);
}

// zT B-fragment layout: element z[n][h] at short index
//   ((hb*128 + kb)*64 + hl + 16*oct)*8 + j   (hb=h>>4, hl=h&15, kb=n>>5, oct=(n>>3)&3, j=n&7)
__device__ __forceinline__ long zt_idx(int n, int h) {
  const int hb = h >> 4, hl = h & 15;
  const int kb = n >> 5, oct = (n >> 3) & 3, j = n & 7;
  return ((long)(hb * 128 + kb) * 64 + hl + 16 * oct) * 8 + j;
}

// ---------------- natural cubic spline -> dX/dt at s=0, 0.5, 1; zero barrier ----
__global__ void k_spline(const float* __restrict__ x,
                         float* __restrict__ dx0, float* __restrict__ dxh,
                         float* __restrict__ dx1, unsigned* __restrict__ bar) {
  const int c = blockIdx.x * 256 + threadIdx.x;
  if (blockIdx.x == 0) { bar[threadIdx.x] = 0u; bar[threadIdx.x + 256] = 0u; }
  float y[16];
#pragma unroll
  for (int t = 0; t < 16; ++t) y[t] = x[t * NI + c];
  float cp[15], dp[15], M[16];
  cp[1] = 0.25f;
  dp[1] = (6.f * (y[2] - 2.f * y[1] + y[0])) * 0.25f;
#pragma unroll
  for (int i = 2; i <= 14; ++i) {
    float ri = 6.f * (y[i + 1] - 2.f * y[i] + y[i - 1]);
    float inv = 1.f / (4.f - cp[i - 1]);
    cp[i] = inv;
    dp[i] = (ri - dp[i - 1]) * inv;
  }
  M[0] = 0.f; M[15] = 0.f;
  M[14] = dp[14];
#pragma unroll
  for (int i = 13; i >= 1; --i) M[i] = dp[i] - cp[i] * M[i + 1];
#pragma unroll
  for (int i = 0; i < 15; ++i) {
    float b = (y[i + 1] - y[i]) - (2.f * M[i] + M[i + 1]) * (1.f / 6.f);
    float cc = 0.5f * M[i];
    float dd = (M[i + 1] - M[i]) * (1.f / 6.f);
    dx0[i * NI + c] = b;
    dxh[i * NI + c] = b + cc + 0.75f * dd;
    dx1[i * NI + c] = b + 2.f * cc + 3.f * dd;
  }
}

struct OdeP {
  const float *x, *We, *be, *adj;
  const float *Wg, *bg, *Wt, *bt, *Wp, *bp, *Wd1, *bd1, *Wd2, *bd2;
  const float *dx0, *dxh, *dx1;
  short *zTa, *zTb;
  float *out;
  unsigned *bar;   // [0..255]: 8 arrival stripes (stride 32); [256]: release flag
};

// ---- grid barrier: striped arrival counters + leader-released epoch flag ----
__device__ __forceinline__ void gbar(const OdeP& p, int bar_i, int bid) {
  __syncthreads();
  if (threadIdx.x == 0) {
    __threadfence();  // release: make zT stores agent-visible
    __hip_atomic_fetch_add(&p.bar[(bid & 7) * 32], 1u,
                           __ATOMIC_RELAXED, __HIP_MEMORY_SCOPE_AGENT);
    const unsigned tgt = (unsigned)(bar_i + 1);
    if (bid == 0) {
#pragma unroll 1
      for (int s2 = 0; s2 < 8; ++s2)
        while (__hip_atomic_load(&p.bar[s2 * 32], __ATOMIC_RELAXED,
                                 __HIP_MEMORY_SCOPE_AGENT) < tgt * 32u)
          __builtin_amdgcn_s_sleep(1);
      __threadfence();
      __hip_atomic_store(&p.bar[256], tgt, __ATOMIC_RELAXED, __HIP_MEMORY_SCOPE_AGENT);
    } else {
      while (__hip_atomic_load(&p.bar[256], __ATOMIC_RELAXED,
                               __HIP_MEMORY_SCOPE_AGENT) < tgt)
        __builtin_amdgcn_s_sleep(1);
    }
  }
  __syncthreads();
  __threadfence();  // acquire: next zT reads fetch fresh data
}

// ---------------- persistent ODE kernel: 256 blocks x 256 threads, 1/CU ----------------
__global__ __launch_bounds__(256, 1) void k_ode(OdeP p) {
  __shared__ __align__(16) short adjs[65536];     // 128 KB: block's 16 adj rows, A-frag order
  __shared__ float zn_s[16][33];
  __shared__ float ze_s[16][33];
  __shared__ float h_s[16][33];
  __shared__ float Wg_s[32][32];
  __shared__ float Wt_s[32][32];
  __shared__ float Wp_s[32][128];
  __shared__ short Wd1_s[512];
  __shared__ float bgt_s[32];
  __shared__ float bp_s[128];
  __shared__ float dsm[33];                       // b_d1[0:16], W_d2[16:32], b_d2[32]

  const int tid = threadIdx.x;
  const int lane = tid & 63;
  const int w = tid >> 6;            // wave 0..3
  const int bid = blockIdx.x;
  const int r0 = bid * 16;
  const int lane8 = lane * 8;
  const int fr = lane & 15, oct = lane >> 4;

  // ---- prologue: stage constants ----
  for (int idx = tid; idx < 1024; idx += 256) {
    Wg_s[idx >> 5][idx & 31] = p.Wg[idx];
    Wt_s[idx >> 5][idx & 31] = p.Wt[idx];
  }
  for (int idx = tid; idx < 4096; idx += 256) ((float*)Wp_s)[idx] = p.Wp[idx];
  for (int idx = tid; idx < 512; idx += 256) Wd1_s[idx] = f2bs(p.Wd1[idx]);
  if (tid < 32) bgt_s[tid] = p.bg[tid] + p.bt[tid];
  if (tid < 128) bp_s[tid] = p.bp[tid];
  if (tid < 16) { dsm[tid] = p.bd1[tid]; dsm[16 + tid] = p.Wd2[tid]; }
  if (tid == 0) dsm[32] = p.bd2[0];

  // ---- adj rows -> LDS bf16 in A-fragment order (done once) ----
  {
    const float* srow = p.adj + (long)(r0 + fr) * NN + w * 1024 + oct * 8;
#pragma unroll 4
    for (int i = 0; i < 32; ++i) {
      const float4 u0 = *(const float4*)(srow + i * 32);
      const float4 u1 = *(const float4*)(srow + i * 32 + 4);
      short8 r;
      r[0] = f2bs(u0.x); r[1] = f2bs(u0.y); r[2] = f2bs(u0.z); r[3] = f2bs(u0.w);
      r[4] = f2bs(u1.x); r[5] = f2bs(u1.y); r[6] = f2bs(u1.z); r[7] = f2bs(u1.w);
      *(short8*)&adjs[(w * 32 + i) * 512 + lane8] = r;
    }
  }

  // ---- encoder for own rows: z0 = x0 @ We + be; init state ----
  float zb[2], k1r[2] = {0.f, 0.f}, k2r[2] = {0.f, 0.f}, k3r[2] = {0.f, 0.f};
#pragma unroll
  for (int e = 0; e < 2; ++e) {
    const int idx = tid + e * 256;
    const int r = idx >> 5, c = idx & 31;
    const int n = r0 + r;
    const float4 xv = *(const float4*)&p.x[n * 4];
    float z0 = p.be[c];
    z0 = fmaf(xv.x, p.We[0 * 32 + c], z0);
    z0 = fmaf(xv.y, p.We[1 * 32 + c], z0);
    z0 = fmaf(xv.z, p.We[2 * 32 + c], z0);
    z0 = fmaf(xv.w, p.We[3 * 32 + c], z0);
    zb[e] = z0;
    ze_s[r][c] = z0;
    h_s[r][c] = z0;          // t=0 decode input
    zn_s[r][c] = 0.f;        // zero accumulators for substep 0
    p.zTa[zt_idx(n, c)] = f2bs(z0);
  }
  __syncthreads();

  // ---- decode t=0 ----
  if (tid < 16) {
    float acc = dsm[32];
#pragma unroll
    for (int jj = 0; jj < 16; ++jj) {
      float hv = dsm[jj];
#pragma unroll
      for (int hh = 0; hh < 32; ++hh) hv = fmaf(h_s[tid][hh], bs2f(Wd1_s[hh * 16 + jj]), hv);
      acc = fmaf(fmaxf(hv, 0.f), dsm[16 + jj], acc);
    }
    p.out[r0 + tid] = 1.f / (1.f + expf(-acc));
  }

  int bar_i = 0;
  gbar(p, bar_i++, bid);   // zTa visible to all blocks

  // ---- 60 RK4 substeps ----
  const int fb = w * 32;
#pragma unroll 1
  for (int s = 0; s < 60; ++s) {
    const int t = s >> 2;
    const int j = (s & 3) + 1;
    const short* zi = (s & 1) ? p.zTb : p.zTa;
    short* zo = (s & 1) ? p.zTa : p.zTb;
    const float* dxp = (j == 1) ? (p.dx0 + t * NI)
                     : (j == 4) ? (p.dx1 + t * NI) : (p.dxh + t * NI);

    // matmul: zn(own 16 rows) = adj @ z ; A from LDS, B from global zT
    f32x4 a0 = {0.f,0.f,0.f,0.f}, a1 = {0.f,0.f,0.f,0.f};
    f32x4 a2 = {0.f,0.f,0.f,0.f}, a3 = {0.f,0.f,0.f,0.f};
#pragma unroll 4
    for (int i = 0; i < 32; i += 2) {
      const int f0 = fb + i, f1 = fb + i + 1;
      const short8 av0 = *(const short8*)&adjs[f0 * 512 + lane8];
      const short8 bv00 = *(const short8*)(zi + (long)f0 * 512 + lane8);
      const short8 bv01 = *(const short8*)(zi + (long)(128 + f0) * 512 + lane8);
      const short8 av1 = *(const short8*)&adjs[f1 * 512 + lane8];
      const short8 bv10 = *(const short8*)(zi + (long)f1 * 512 + lane8);
      const short8 bv11 = *(const short8*)(zi + (long)(128 + f1) * 512 + lane8);
      a0 = __builtin_amdgcn_mfma_f32_16x16x32_bf16(av0, bv00, a0, 0, 0, 0);
      a1 = __builtin_amdgcn_mfma_f32_16x16x32_bf16(av0, bv01, a1, 0, 0, 0);
      a2 = __builtin_amdgcn_mfma_f32_16x16x32_bf16(av1, bv10, a2, 0, 0, 0);
      a3 = __builtin_amdgcn_mfma_f32_16x16x32_bf16(av1, bv11, a3, 0, 0, 0);
    }
    const f32x4 acc0 = a0 + a2, acc1 = a1 + a3;
    {
      const int crow = (lane >> 4) * 4;   // C/D: col=lane&15, row=quad*4+reg
      const int ccol = lane & 15;
#pragma unroll
      for (int q = 0; q < 4; ++q) {
        atomicAdd(&zn_s[crow + q][ccol], acc0[q]);
        atomicAdd(&zn_s[crow + q][ccol + 16], acc1[q]);
      }
    }
    __syncthreads();

    // h = relu(zn@Wg + ze@Wt + bg + bt)
#pragma unroll
    for (int e = 0; e < 2; ++e) {
      const int idx = tid + e * 256;
      const int r = idx >> 5, c = idx & 31;
      float hv = bgt_s[c];
#pragma unroll
      for (int kk = 0; kk < 32; ++kk)
        hv = fmaf(zn_s[r][kk], Wg_s[kk][c], fmaf(ze_s[r][kk], Wt_s[kk][c], hv));
      h_s[r][c] = fmaxf(hv, 0.f);
    }
    __syncthreads();

    // sens/einsum + RK4 state update (all per-row state in registers)
    float znew[2];
#pragma unroll
    for (int e = 0; e < 2; ++e) {
      const int idx = tid + e * 256;
      const int r = idx >> 5, c = idx & 31;
      const int row = r0 + r;
      const float4 dxv = *(const float4*)&dxp[row * 4];
      float kv = 0.f;
#pragma unroll
      for (int i = 0; i < 4; ++i) {
        float sv = bp_s[c * 4 + i];
#pragma unroll
        for (int hp = 0; hp < 32; ++hp) sv = fmaf(h_s[r][hp], Wp_s[hp][c * 4 + i], sv);
        const float dx = (i == 0) ? dxv.x : (i == 1) ? dxv.y : (i == 2) ? dxv.z : dxv.w;
        kv = fmaf(sv, dx, kv);
      }
      float zn2;
      if (j == 4) {
        zn2 = zb[e] + (k1r[e] + 2.f * k2r[e] + 2.f * k3r[e] + kv) * (1.f / 6.f);
        zb[e] = zn2;
      } else {
        if (j == 1) k1r[e] = kv; else if (j == 2) k2r[e] = kv; else k3r[e] = kv;
        zn2 = zb[e] + ((j == 3) ? 1.f : 0.5f) * kv;
      }
      znew[e] = zn2;
      zn_s[r][c] = 0.f;            // re-zero accumulators for next substep
      ze_s[r][c] = zn2;            // safe: ze_s reads finished at the h barrier
      zo[zt_idx(row, c)] = f2bs(zn2);
    }

    if (j == 4) {                  // fused decode of z_{t+1}
      __syncthreads();             // all sens reads of h_s done
#pragma unroll
      for (int e = 0; e < 2; ++e) {
        const int idx = tid + e * 256;
        h_s[idx >> 5][idx & 31] = znew[e];
      }
      __syncthreads();
      if (tid < 16) {
        float acc = dsm[32];
#pragma unroll
        for (int jj = 0; jj < 16; ++jj) {
          float hv = dsm[jj];
#pragma unroll
          for (int hh = 0; hh < 32; ++hh)
            hv = fmaf(h_s[tid][hh], bs2f(Wd1_s[hh * 16 + jj]), hv);
          acc = fmaf(fmaxf(hv, 0.f), dsm[16 + jj], acc);
        }
        p.out[(t + 1) * NN + r0 + tid] = 1.f / (1.f + expf(-acc));
      }
    }

    if (s < 59) gbar(p, bar_i++, bid);
  }
}

extern "C" void kernel_launch(void* const* d_in, const int* in_sizes, int n_in,
                              void* d_out, int out_size, void* d_ws, size_t ws_size,
                              hipStream_t stream) {
  (void)in_sizes; (void)n_in; (void)out_size; (void)ws_size;
  const float* x      = (const float*)d_in[0];
  const float* adj    = (const float*)d_in[1];
  const float* W_enc  = (const float*)d_in[2];
  const float* b_enc  = (const float*)d_in[3];
  const float* W_gcn  = (const float*)d_in[4];
  const float* b_gcn  = (const float*)d_in[5];
  const float* W_time = (const float*)d_in[6];
  const float* b_time = (const float*)d_in[7];
  const float* W_proj = (const float*)d_in[8];
  const float* b_proj = (const float*)d_in[9];
  const float* W_d1   = (const float*)d_in[10];
  const float* b_d1   = (const float*)d_in[11];
  const float* W_d2   = (const float*)d_in[12];
  const float* b_d2   = (const float*)d_in[13];

  // workspace: barrier (2 KB) + dx arrays (2.95 MB) + zT ping/pong (0.5 MB)
  unsigned* bar = (unsigned*)d_ws;          // 512 uints
  float* dx0 = (float*)(bar + 512);
  float* dxh = dx0 + 15 * NI;
  float* dx1 = dxh + 15 * NI;
  short* zTa = (short*)(dx1 + 15 * NI);
  short* zTb = zTa + HH * NN;

  k_spline<<<64, 256, 0, stream>>>(x, dx0, dxh, dx1, bar);

  OdeP p;
  p.x = x; p.We = W_enc; p.be = b_enc; p.adj = adj;
  p.Wg = W_gcn; p.bg = b_gcn; p.Wt = W_time; p.bt = b_time;
  p.Wp = W_proj; p.bp = b_proj; p.Wd1 = W_d1; p.bd1 = b_d1;
  p.Wd2 = W_d2; p.bd2 = b_d2;
  p.dx0 = dx0; p.dxh = dxh; p.dx1 = dx1;
  p.zTa = zTa; p.zTb = zTb;
  p.out = (float*)d_out; p.bar = bar;

  void* args[] = { &p };
  hipError_t rc = hipLaunchCooperativeKernel((const void*)k_ode, dim3(256), dim3(256),
                                             args, 0, stream);
  if (rc != hipSuccess) {
    // fallback: plain launch — 1 block/CU sizing keeps all 256 blocks resident
    k_ode<<<256, 256, 0, stream>>>(p);
  }
}

// Round 6
// 783.733 us; speedup vs baseline: 2.9397x; 2.9397x over previous
//
#include <hip/hip_runtime.h>
#include <hip/hip_bf16.h>

#define NN 4096
#define NI 16384   // N*I
#define HH 32

typedef __attribute__((ext_vector_type(8))) short short8;
typedef __attribute__((ext_vector_type(4))) float f32x4;

__device__ __forceinline__ short f2bs(float f) {
  __hip_bfloat16 b = __float2bfloat16(f);
  return *(short*)&b;
}

// ---- adj f32 -> bf16, permuted into MFMA A-fragment order ----
// Fragment (R, W, i) = 64 lanes x 8 bf16, contiguous 1 KB:
//   element: adj[R*16 + (lane&15)][W*512 + i*32 + (lane>>4)*8 + j], j=0..7
__global__ __launch_bounds__(512) void k_cvt(const float* __restrict__ a,
                                             short* __restrict__ ab) {
  const int tid = threadIdx.x;
  const int W = tid >> 6, lane = tid & 63;
  const int fr = lane & 15, oct = lane >> 4;
  const int R = blockIdx.x;
  const float* srow = a + (long)(R * 16 + fr) * NN + W * 512 + oct * 8;
  short* drow = ab + ((long)(R * 8 + W) * 16) * 512 + lane * 8;
#pragma unroll 4
  for (int i = 0; i < 16; ++i) {
    const float4 u0 = *(const float4*)(srow + i * 32);
    const float4 u1 = *(const float4*)(srow + i * 32 + 4);
    short8 r;
    r[0] = f2bs(u0.x); r[1] = f2bs(u0.y); r[2] = f2bs(u0.z); r[3] = f2bs(u0.w);
    r[4] = f2bs(u1.x); r[5] = f2bs(u1.y); r[6] = f2bs(u1.z); r[7] = f2bs(u1.w);
    *(short8*)(drow + i * 512) = r;
  }
}

// zT B-fragment layout: element z[n][h] at short index
//   ((hb*128 + kb)*64 + hl + 16*oct)*8 + j  (hb=h>>4, hl=h&15, kb=n>>5, oct=(n>>3)&3, j=n&7)
__device__ __forceinline__ long zt_idx(int n, int h) {
  const int hb = h >> 4, hl = h & 15;
  const int kb = n >> 5, oct = (n >> 3) & 3, j = n & 7;
  return ((long)(hb * 128 + kb) * 64 + hl + 16 * oct) * 8 + j;
}

// ---------------- natural cubic spline -> dX/dt at s=0, 0.5, 1 ----------------
__global__ void k_spline(const float* __restrict__ x,
                         float* __restrict__ dx0, float* __restrict__ dxh,
                         float* __restrict__ dx1) {
  const int c = blockIdx.x * 256 + threadIdx.x;
  float y[16];
#pragma unroll
  for (int t = 0; t < 16; ++t) y[t] = x[t * NI + c];
  float cp[15], dp[15], M[16];
  cp[1] = 0.25f;
  dp[1] = (6.f * (y[2] - 2.f * y[1] + y[0])) * 0.25f;
#pragma unroll
  for (int i = 2; i <= 14; ++i) {
    float ri = 6.f * (y[i + 1] - 2.f * y[i] + y[i - 1]);
    float inv = 1.f / (4.f - cp[i - 1]);
    cp[i] = inv;
    dp[i] = (ri - dp[i - 1]) * inv;
  }
  M[0] = 0.f; M[15] = 0.f;
  M[14] = dp[14];
#pragma unroll
  for (int i = 13; i >= 1; --i) M[i] = dp[i] - cp[i] * M[i + 1];
#pragma unroll
  for (int i = 0; i < 15; ++i) {
    float b = (y[i + 1] - y[i]) - (2.f * M[i] + M[i + 1]) * (1.f / 6.f);
    float cc = 0.5f * M[i];
    float dd = (M[i + 1] - M[i]) * (1.f / 6.f);
    dx0[i * NI + c] = b;
    dxh[i * NI + c] = b + cc + 0.75f * dd;
    dx1[i * NI + c] = b + 2.f * cc + 3.f * dd;
  }
}

// ---------------- encoder ----------------
__global__ void k_enc(const float* __restrict__ x,
                      const float* __restrict__ We,
                      const float* __restrict__ be,
                      float* __restrict__ zcur, float* __restrict__ ze,
                      short* __restrict__ zT) {
  const int g = blockIdx.x * 256 + threadIdx.x;
  const int n = g >> 5, h = g & 31;
  float acc = be[h];
#pragma unroll
  for (int i = 0; i < 4; ++i) acc = fmaf(x[n * 4 + i], We[i * 32 + h], acc);
  zcur[g] = acc;
  ze[g] = acc;
  zT[zt_idx(n, h)] = f2bs(acc);
}

// ---------------- decoder for t=0 ----------------
__global__ void k_dec0(const float* __restrict__ z,
                       const float* __restrict__ W1,
                       const float* __restrict__ b1,
                       const float* __restrict__ W2,
                       const float* __restrict__ b2,
                       float* __restrict__ out) {
  __shared__ float W1s[32][17];
  __shared__ float b1s[16], W2s[16], b2s;
  const int tid = threadIdx.x;
  for (int idx = tid; idx < 512; idx += 256) W1s[idx >> 4][idx & 15] = W1[idx];
  if (tid < 16) { b1s[tid] = b1[tid]; W2s[tid] = W2[tid]; }
  if (tid == 0) b2s = b2[0];
  __syncthreads();
  const int n = blockIdx.x * 256 + tid;
  const float* zr = z + (long)n * 32;
  float zv[32];
#pragma unroll
  for (int hh = 0; hh < 32; ++hh) zv[hh] = zr[hh];
  float acc = b2s;
#pragma unroll
  for (int jj = 0; jj < 16; ++jj) {
    float hv = b1s[jj];
#pragma unroll
    for (int hh = 0; hh < 32; ++hh) hv = fmaf(zv[hh], W1s[hh][jj], hv);
    acc = fmaf(fmaxf(hv, 0.f), W2s[jj], acc);
  }
  out[n] = 1.f / (1.f + expf(-acc));
}

// ---------------- one vector-field evaluation ----------------
// 1024 threads = 16 waves; block owns 16 rows; wave w covers K in [w*256, +256).
__global__ __launch_bounds__(1024) void k_vf(
    const short* __restrict__ adjb,
    const short* __restrict__ zT_in,
    short* __restrict__ zT_out,
    float* __restrict__ z_eval,
    const float* __restrict__ z_base,
    float* __restrict__ z_next,
    float* __restrict__ kout,
    const float* __restrict__ k1, const float* __restrict__ k2,
    const float* __restrict__ k3,
    const float* __restrict__ dxsel,
    const float* __restrict__ Wg, const float* __restrict__ bg,
    const float* __restrict__ Wt, const float* __restrict__ bt,
    const float* __restrict__ Wp, const float* __restrict__ bp,
    const float* __restrict__ Wd1, const float* __restrict__ bd1,
    const float* __restrict__ Wd2, const float* __restrict__ bd2,
    float* __restrict__ out, int out_base, int j) {
  __shared__ float red2[16][32][17];   // [row][col][wave] pad-17: 34.8 KB
  __shared__ float zn_s[16][33];
  __shared__ float h_s[16][33];
  __shared__ float ze_s[16][33];
  __shared__ float Wg_s[32][32];
  __shared__ float Wt_s[32][32];
  __shared__ float Wp_s[32][136];      // row stride 544 B (16B-aligned), float4-readable
  __shared__ float Wd1_s[32][16];
  __shared__ float bgt_s[32];
  __shared__ float bp_s[128];
  __shared__ float dsm[33];            // b_d1[0:16], W_d2[16:32], b_d2[32]

  const int tid = threadIdx.x;
  const int lane = tid & 63;
  const int w = tid >> 6;              // wave 0..15
  const int r0 = blockIdx.x * 16;
  const int lane8 = lane * 8;

  // ---- MFMA: zn = adj @ z, rows r0..r0+15; frag f = w*8+i; loads 1KB coalesced ----
  f32x4 a0 = {0.f,0.f,0.f,0.f}, a1 = {0.f,0.f,0.f,0.f};
  const short* ap  = adjb + ((long)(blockIdx.x * 128 + w * 8)) * 512 + lane8;
  const short* b0p = zT_in + ((long)(w * 8)) * 512 + lane8;          // hb=0
  const short* b1p = zT_in + ((long)(128 + w * 8)) * 512 + lane8;    // hb=1
#pragma unroll
  for (int i = 0; i < 8; ++i) {
    const short8 av = *(const short8*)(ap + i * 512);
    const short8 b0 = *(const short8*)(b0p + i * 512);
    const short8 b1 = *(const short8*)(b1p + i * 512);
    a0 = __builtin_amdgcn_mfma_f32_16x16x32_bf16(av, b0, a0, 0, 0, 0);
    a1 = __builtin_amdgcn_mfma_f32_16x16x32_bf16(av, b1, a1, 0, 0, 0);
  }

  // ---- stage small operands (placed after load issue; visible after barrier) ----
  for (int idx = tid; idx < 1024; idx += 1024) { }  // (no-op; keep structure simple)
  if (tid < 1024) {
    if (tid < 512) {
      Wg_s[tid >> 5][tid & 31] = Wg[tid];
      Wt_s[tid >> 5][tid & 31] = Wt[tid];
    } else {
      const int q = tid - 512;
      Wg_s[(q + 512) >> 5][q & 31] = Wg[512 + q];
      Wt_s[(q + 512) >> 5][q & 31] = Wt[512 + q];
    }
  }
  for (int idx = tid; idx < 4096; idx += 1024)
    Wp_s[idx >> 7][idx & 127] = Wp[idx];
  if (tid < 512) Wd1_s[tid >> 4][tid & 15] = Wd1[tid];
  if (tid < 32) bgt_s[tid] = bg[tid] + bt[tid];
  if (tid < 128) bp_s[tid] = bp[tid];
  if (tid < 512) ze_s[tid >> 5][tid & 31] = z_eval[r0 * 32 + tid];
  if (tid < 16) { dsm[tid] = bd1[tid]; dsm[16 + tid] = Wd2[tid]; }
  if (tid == 0) dsm[32] = bd2[0];

  // ---- write MFMA partials: red2[row][col][wave] ----
  {
    const int crow = (lane >> 4) * 4;   // C/D: col=lane&15, row=quad*4+reg
    const int ccol = lane & 15;
#pragma unroll
    for (int q = 0; q < 4; ++q) {
      red2[crow + q][ccol][w] = a0[q];
      red2[crow + q][ccol + 16][w] = a1[q];
    }
  }
  __syncthreads();

  // ---- cross-wave reduction: thread (r,c) sums 16 partials ----
  const int r = (tid >> 5) & 15, c = tid & 31;
  if (tid < 512) {
    float zn = 0.f;
#pragma unroll
    for (int q = 0; q < 16; ++q) zn += red2[r][c][q];
    zn_s[r][c] = zn;
  }
  __syncthreads();

  // ---- h = relu(zn@Wg + ze@Wt + bg + bt) ----
  if (tid < 512) {
    float hv = bgt_s[c];
#pragma unroll
    for (int kk = 0; kk < 32; ++kk)
      hv = fmaf(zn_s[r][kk], Wg_s[kk][c], fmaf(ze_s[r][kk], Wt_s[kk][c], hv));
    h_s[r][c] = fmaxf(hv, 0.f);
  }
  __syncthreads();

  // ---- sens/einsum + RK4 update ----
  float znew = 0.f;
  if (tid < 512) {
    const int row = r0 + r;
    float hr[32];
#pragma unroll
    for (int hp = 0; hp < 32; ++hp) hr[hp] = h_s[r][hp];   // broadcast reads
    float s0 = bp_s[c * 4], s1 = bp_s[c * 4 + 1], s2 = bp_s[c * 4 + 2], s3 = bp_s[c * 4 + 3];
#pragma unroll
    for (int hp = 0; hp < 32; ++hp) {
      const float4 wv = *(const float4*)&Wp_s[hp][c * 4];  // aligned b128, conflict-free
      s0 = fmaf(hr[hp], wv.x, s0);
      s1 = fmaf(hr[hp], wv.y, s1);
      s2 = fmaf(hr[hp], wv.z, s2);
      s3 = fmaf(hr[hp], wv.w, s3);
    }
    const float4 dxv = *(const float4*)&dxsel[row * 4];
    const float kv = s0 * dxv.x + s1 * dxv.y + s2 * dxv.z + s3 * dxv.w;
    const long g = (long)row * 32 + c;
    if (j == 4) {
      znew = z_base[g] + (k1[g] + 2.f * k2[g] + 2.f * k3[g] + kv) * (1.f / 6.f);
      z_next[g] = znew;
    } else {
      kout[g] = kv;
      znew = z_base[g] + ((j == 3) ? 1.f : 0.5f) * kv;
    }
    z_eval[g] = znew;
    zT_out[zt_idx(row, c)] = f2bs(znew);
  }

  // ---- fused decoder for z_{t+1} (j==4 only) ----
  if (j == 4) {
    __syncthreads();                    // all reads of h_s/zn_s done
    if (tid < 512) zn_s[r][c] = znew;   // final-z tile
    __syncthreads();
    if (tid < 16) {
      float acc = dsm[32];
#pragma unroll
      for (int jj = 0; jj < 16; ++jj) {
        float hv = dsm[jj];
#pragma unroll
        for (int hh = 0; hh < 32; ++hh) hv = fmaf(zn_s[tid][hh], Wd1_s[hh][jj], hv);
        acc = fmaf(fmaxf(hv, 0.f), dsm[16 + jj], acc);
      }
      out[out_base + r0 + tid] = 1.f / (1.f + expf(-acc));
    }
  }
}

extern "C" void kernel_launch(void* const* d_in, const int* in_sizes, int n_in,
                              void* d_out, int out_size, void* d_ws, size_t ws_size,
                              hipStream_t stream) {
  (void)in_sizes; (void)n_in; (void)out_size; (void)ws_size;
  const float* x      = (const float*)d_in[0];
  const float* adj    = (const float*)d_in[1];
  const float* W_enc  = (const float*)d_in[2];
  const float* b_enc  = (const float*)d_in[3];
  const float* W_gcn  = (const float*)d_in[4];
  const float* b_gcn  = (const float*)d_in[5];
  const float* W_time = (const float*)d_in[6];
  const float* b_time = (const float*)d_in[7];
  const float* W_proj = (const float*)d_in[8];
  const float* b_proj = (const float*)d_in[9];
  const float* W_d1   = (const float*)d_in[10];
  const float* b_d1   = (const float*)d_in[11];
  const float* W_d2   = (const float*)d_in[12];
  const float* b_d2   = (const float*)d_in[13];
  float* out = (float*)d_out;

  float* dx0   = (float*)d_ws;
  float* dxh   = dx0 + 15 * NI;
  float* dx1   = dxh + 15 * NI;
  float* zcur  = dx1 + 15 * NI;
  float* znext = zcur + NN * HH;
  float* zev   = znext + NN * HH;
  float* k1b   = zev + NN * HH;
  float* k2b   = k1b + NN * HH;
  float* k3b   = k2b + NN * HH;
  short* zTa   = (short*)(k3b + NN * HH);
  short* zTb   = zTa + HH * NN;
  short* adjb  = zTb + HH * NN;             // 32 MB, frag order

  k_cvt<<<256, 512, 0, stream>>>(adj, adjb);
  k_spline<<<64, 256, 0, stream>>>(x, dx0, dxh, dx1);
  k_enc<<<512, 256, 0, stream>>>(x, W_enc, b_enc, zcur, zev, zTa);
  k_dec0<<<16, 256, 0, stream>>>(zcur, W_d1, b_d1, W_d2, b_d2, out);

  short* zin = zTa;
  short* zout = zTb;
  for (int t = 0; t < 15; ++t) {
    const float* ds[4] = { dx0 + t * NI, dxh + t * NI, dxh + t * NI, dx1 + t * NI };
    for (int j = 1; j <= 4; ++j) {
      float* ko = (j == 1) ? k1b : (j == 2) ? k2b : k3b;
      k_vf<<<256, 1024, 0, stream>>>(adjb, zin, zout, zev, zcur, znext, ko,
                                     k1b, k2b, k3b, ds[j - 1],
                                     W_gcn, b_gcn, W_time, b_time, W_proj, b_proj,
                                     W_d1, b_d1, W_d2, b_d2, out, (t + 1) * NN, j);
      short* tmp = zin; zin = zout; zout = tmp;
    }
    float* tz = zcur; zcur = znext; znext = tz;
  }
}